// Round 2
// baseline (908.324 us; speedup 1.0000x reference)
//
#include <hip/hip_runtime.h>

#define MM 8192
#define BATCH 16
#define HIDN 32
#define WIN 64
#define NNZ 131072
#define EXTRA 32
#define EPS 1e-5f
#define NSTAT 131072.0f   // BATCH*MM

// ---------- utility ----------
__global__ void k_zero(float* p, int n) {
    int i = blockIdx.x * 256 + threadIdx.x;
    if (i < n) p[i] = 0.f;
}

// ---------- CSR build ----------
__global__ void k_hist(const int* __restrict__ row, int* cnt) {
    int e = blockIdx.x * 256 + threadIdx.x;
    atomicAdd(&cnt[row[e]], 1);
}

__global__ void k_scan(const int* __restrict__ cnt, int* __restrict__ ptr, int* __restrict__ cursor) {
    __shared__ int part[1024];
    int t = threadIdx.x;
    int base = t * 8;
    int pre[8];
    int s = 0;
#pragma unroll
    for (int i = 0; i < 8; i++) { pre[i] = s; s += cnt[base + i]; }
    part[t] = s;
    __syncthreads();
    for (int off = 1; off < 1024; off <<= 1) {
        int v = (t >= off) ? part[t - off] : 0;
        __syncthreads();
        part[t] += v;
        __syncthreads();
    }
    int offs = (t == 0) ? 0 : part[t - 1];
#pragma unroll
    for (int i = 0; i < 8; i++) {
        ptr[base + i] = offs + pre[i];
        cursor[base + i] = offs + pre[i];
    }
    if (t == 1023) ptr[8192] = part[1023];
}

__global__ void k_scatter(const int* __restrict__ row, const int* __restrict__ col,
                          const float* __restrict__ val, int* cursor,
                          int* __restrict__ csr_col, float* __restrict__ csr_val) {
    int e = blockIdx.x * 256 + threadIdx.x;
    int r = row[e];
    int p = atomicAdd(&cursor[r], 1);
    csr_col[p] = col[e];
    csr_val[p] = val[e];
}

// ---------- layer 1 linear: z[m*512 + b*32 + h] = sum_f x[b,m,f] * W1[f,h] ----------
__global__ __launch_bounds__(256) void k_lin1(const float* __restrict__ x,
                                              const float* __restrict__ W1,
                                              float* __restrict__ z) {
    __shared__ float xs[32 * 64];
    int t = threadIdx.x;
    int p0 = blockIdx.x * 32;                 // pair index p = b*M + m
    const float4* x4 = (const float4*)(x + (size_t)p0 * 64);
    float4* xs4 = (float4*)xs;
    xs4[t] = x4[t];
    xs4[t + 256] = x4[t + 256];
    int lane = t & 63;
    int h = lane & 31;
    int sub = lane >> 5;
    int wv = t >> 6;
    float wcol[64];
#pragma unroll
    for (int f = 0; f < 64; f++) wcol[f] = W1[f * 32 + h];
    __syncthreads();
    int b = p0 >> 13;
    int m0 = p0 & 8191;
#pragma unroll
    for (int it = 0; it < 4; it++) {
        int pl = wv * 8 + it * 2 + sub;       // local pair 0..31
        const float4* xr = (const float4*)(xs + pl * 64);
        float acc = 0.f;
#pragma unroll
        for (int i = 0; i < 16; i++) {
            float4 v = xr[i];
            acc += v.x * wcol[4*i] + v.y * wcol[4*i+1] + v.z * wcol[4*i+2] + v.w * wcol[4*i+3];
        }
        z[(size_t)(m0 + pl) * 512 + b * 32 + h] = acc;
    }
}

// ---------- SpMM: y[r,:] = sum_{e in row r} val_e * z[col_e,:]  (width 512) ----------
__global__ __launch_bounds__(256) void k_spmm(const float* __restrict__ z,
                                              const int* __restrict__ ptr,
                                              const int* __restrict__ cols,
                                              const float* __restrict__ vals,
                                              float* __restrict__ y) {
    int t = threadIdx.x;
    int lane = t & 63;
    int r = blockIdx.x * 4 + (t >> 6);
    int e0 = ptr[r], e1 = ptr[r + 1];
    float4 a0 = {0.f, 0.f, 0.f, 0.f};
    float4 a1 = {0.f, 0.f, 0.f, 0.f};
    const float4* z4 = (const float4*)z;
    for (int e = e0; e < e1; e++) {
        int c = cols[e];
        float v = vals[e];
        float4 b0 = z4[(size_t)c * 128 + lane];
        float4 b1 = z4[(size_t)c * 128 + 64 + lane];
        a0.x += v * b0.x; a0.y += v * b0.y; a0.z += v * b0.z; a0.w += v * b0.w;
        a1.x += v * b1.x; a1.y += v * b1.y; a1.z += v * b1.z; a1.w += v * b1.w;
    }
    float4* y4 = (float4*)y;
    y4[(size_t)r * 128 + lane] = a0;
    y4[(size_t)r * 128 + 64 + lane] = a1;
}

// ---------- channel stats: sum and sumsq per channel (h = idx%32) ----------
__global__ __launch_bounds__(256) void k_stats(const float* __restrict__ y, float* __restrict__ st) {
    int t = threadIdx.x;
    int idx = blockIdx.x * 256 + t;
    float s1 = 0.f, s2 = 0.f;
    for (int i = idx; i < MM * 512; i += 512 * 256) {
        float v = y[i];
        s1 += v; s2 += v * v;
    }
    s1 += __shfl_xor(s1, 32, 64);
    s2 += __shfl_xor(s2, 32, 64);
    __shared__ float ls[64];
    if (t < 64) ls[t] = 0.f;
    __syncthreads();
    int ch = t & 31;
    if ((t & 32) == 0) { atomicAdd(&ls[ch], s1); atomicAdd(&ls[32 + ch], s2); }
    __syncthreads();
    if (t < 64) atomicAdd(&st[t], ls[t]);
}

// ---------- BN1+ReLU fused with layer-2 linear ----------
__global__ __launch_bounds__(256) void k_lin2(const float* __restrict__ y,
                                              const float* __restrict__ st,
                                              const float* __restrict__ g,
                                              const float* __restrict__ be,
                                              const float* __restrict__ W2,
                                              float* __restrict__ z) {
    __shared__ float xs[64 * 32];
    int t = threadIdx.x;
    int ch = t & 31;
    float mean = st[ch] * (1.f / NSTAT);
    float var = st[32 + ch] * (1.f / NSTAT) - mean * mean;
    float a = g[ch] * rsqrtf(var + EPS);
    float c = be[ch] - mean * a;
    int q0 = blockIdx.x * 64;                 // q = m*16 + b
    const float* src = y + (size_t)q0 * 32;
#pragma unroll
    for (int i = 0; i < 8; i++) {
        float v = src[t + i * 256];
        xs[t + i * 256] = fmaxf(a * v + c, 0.f);
    }
    int lane = t & 63;
    int h2 = lane & 31;
    int sub = lane >> 5;
    int wv = t >> 6;
    float wcol[32];
#pragma unroll
    for (int h = 0; h < 32; h++) wcol[h] = W2[h * 32 + h2];
    __syncthreads();
    float* zo = z + (size_t)q0 * 32;
#pragma unroll
    for (int it = 0; it < 8; it++) {
        int ql = wv * 16 + it * 2 + sub;
        const float4* xr = (const float4*)(xs + ql * 32);
        float acc = 0.f;
#pragma unroll
        for (int i = 0; i < 8; i++) {
            float4 v = xr[i];
            acc += v.x * wcol[4*i] + v.y * wcol[4*i+1] + v.z * wcol[4*i+2] + v.w * wcol[4*i+3];
        }
        zo[ql * 32 + h2] = acc;
    }
}

// ---------- head partials: partial[blk, b, n] = sum_{m in blk, h} relu(BN2(y))[b,m,h] * fc1_w[m*32+h, n]
// 512 blocks x 16 m-rows. Two 128-thread halves, each owns 8 m's and all 128 float4 columns.
__global__ __launch_bounds__(256) void k_head(const float* __restrict__ y,
                                              const float* __restrict__ st,
                                              const float* __restrict__ g,
                                              const float* __restrict__ be,
                                              const float* __restrict__ fw,
                                              float* __restrict__ partial) {
    __shared__ float xsh[16 * 512];           // stage: xsh[mi*512 + h*16 + b]; reused as merge buf
    int t = threadIdx.x;
    int ch = t & 31;
    float mean = st[ch] * (1.f / NSTAT);
    float var = st[32 + ch] * (1.f / NSTAT) - mean * mean;
    float a = g[ch] * rsqrtf(var + EPS);
    float c = be[ch] - mean * a;
    int m0 = blockIdx.x * 16;
    // stage all 16 rows: y[m*512 + t] has b=t>>5 (0..7), h=t&31; +256 -> b+8
#pragma unroll
    for (int mi = 0; mi < 16; mi++) {
        int m = m0 + mi;
        float v0 = y[(size_t)m * 512 + t];
        float v1 = y[(size_t)m * 512 + t + 256];
        xsh[mi * 512 + ch * 16 + (t >> 5)]     = fmaxf(a * v0 + c, 0.f);
        xsh[mi * 512 + ch * 16 + (t >> 5) + 8] = fmaxf(a * v1 + c, 0.f);
    }
    __syncthreads();
    int tcol = t & 127;                       // float4 column 0..127 (covers all 512 cols)
    int half = t >> 7;                        // 0 or 1
    float4 acc[16];
#pragma unroll
    for (int b = 0; b < 16; b++) acc[b] = make_float4(0.f, 0.f, 0.f, 0.f);
    const float4* fw4 = (const float4*)fw;
    for (int mi = half * 8; mi < half * 8 + 8; mi++) {
        int m = m0 + mi;
        const float* xrow = xsh + mi * 512;
#pragma unroll 4
        for (int h = 0; h < 32; h++) {
            float4 w = fw4[(size_t)(m * 32 + h) * 128 + tcol];
            const float4* lt4 = (const float4*)(xrow + h * 16);
#pragma unroll
            for (int i = 0; i < 4; i++) {
                float4 Xi = lt4[i];
                acc[4*i+0].x += Xi.x * w.x; acc[4*i+0].y += Xi.x * w.y; acc[4*i+0].z += Xi.x * w.z; acc[4*i+0].w += Xi.x * w.w;
                acc[4*i+1].x += Xi.y * w.x; acc[4*i+1].y += Xi.y * w.y; acc[4*i+1].z += Xi.y * w.z; acc[4*i+1].w += Xi.y * w.w;
                acc[4*i+2].x += Xi.z * w.x; acc[4*i+2].y += Xi.z * w.y; acc[4*i+2].z += Xi.z * w.z; acc[4*i+2].w += Xi.z * w.w;
                acc[4*i+3].x += Xi.w * w.x; acc[4*i+3].y += Xi.w * w.y; acc[4*i+3].z += Xi.w * w.z; acc[4*i+3].w += Xi.w * w.w;
            }
        }
    }
    __syncthreads();                          // xsh reads done; reuse as merge buffer
    float4* mrg = (float4*)xsh;               // mrg[b*128 + tcol], 16*128 float4 = 32 KB
    if (half == 1) {
#pragma unroll
        for (int b = 0; b < 16; b++) mrg[b * 128 + tcol] = acc[b];
    }
    __syncthreads();
    if (half == 0) {
        float4* po = (float4*)(partial + (size_t)blockIdx.x * 8192);
#pragma unroll
        for (int b = 0; b < 16; b++) {
            float4 o = mrg[b * 128 + tcol];
            acc[b].x += o.x; acc[b].y += o.y; acc[b].z += o.z; acc[b].w += o.w;
            po[b * 128 + tcol] = acc[b];
        }
    }
}

// ---------- fold 512 partials -> 8 ----------
__global__ __launch_bounds__(256) void k_red(const float* __restrict__ partial, float* __restrict__ red) {
    int tid = blockIdx.x * 256 + threadIdx.x;   // 0..65535
    int elem = tid & 8191;
    int p8 = tid >> 13;                         // 0..7
    const float* pp = partial + (size_t)p8 * 64 * 8192 + elem;
    float s0 = 0.f, s1 = 0.f, s2 = 0.f, s3 = 0.f;
    for (int k = 0; k < 64; k += 4) {
        s0 += pp[(size_t)(k + 0) * 8192];
        s1 += pp[(size_t)(k + 1) * 8192];
        s2 += pp[(size_t)(k + 2) * 8192];
        s3 += pp[(size_t)(k + 3) * 8192];
    }
    red[p8 * 8192 + elem] = (s0 + s1) + (s2 + s3);
}

// ---------- finish: sum 8 partials + extras + fc1_b, relu, fc2 ----------
__global__ __launch_bounds__(512) void k_final(const float* __restrict__ red,
                                               const float* __restrict__ ex,
                                               const float* __restrict__ fw,
                                               const float* __restrict__ fb1,
                                               const float* __restrict__ fw2,
                                               const float* __restrict__ fb2,
                                               float* __restrict__ out) {
    int b = blockIdx.x;
    int n = threadIdx.x;
    float v = fb1[n];
#pragma unroll
    for (int p = 0; p < 8; p++) v += red[p * 8192 + b * 512 + n];
#pragma unroll
    for (int e = 0; e < 32; e++)
        v += ex[b * 32 + e] * fw[(size_t)(262144 + e) * 512 + n];
    float h = fmaxf(v, 0.f);
    float p0 = h * fw2[n * 2];
    float p1 = h * fw2[n * 2 + 1];
#pragma unroll
    for (int off = 32; off > 0; off >>= 1) {
        p0 += __shfl_xor(p0, off, 64);
        p1 += __shfl_xor(p1, off, 64);
    }
    __shared__ float ls[16];
    int wv = n >> 6;
    if ((n & 63) == 0) { ls[wv * 2] = p0; ls[wv * 2 + 1] = p1; }
    __syncthreads();
    if (n == 0) {
        float s0 = 0.f, s1 = 0.f;
        for (int w = 0; w < 8; w++) { s0 += ls[w * 2]; s1 += ls[w * 2 + 1]; }
        out[b * 2 + 0] = s0 + fb2[0];
        out[b * 2 + 1] = s1 + fb2[1];
    }
}

extern "C" void kernel_launch(void* const* d_in, const int* in_sizes, int n_in,
                              void* d_out, int out_size, void* d_ws, size_t ws_size,
                              hipStream_t stream) {
    const float* inputs = (const float*)d_in[0];
    const float* ex     = (const float*)d_in[1];
    const int*   erow   = (const int*)d_in[2];
    const int*   ecol   = (const int*)d_in[3];
    const float* evalp  = (const float*)d_in[4];
    const float* W1     = (const float*)d_in[5];
    // d_in[6] = b1 (cancels exactly in BN)
    const float* g1     = (const float*)d_in[7];
    const float* be1    = (const float*)d_in[8];
    const float* W2     = (const float*)d_in[9];
    // d_in[10] = b2 (cancels exactly in BN)
    const float* g2     = (const float*)d_in[11];
    const float* be2    = (const float*)d_in[12];
    const float* fc1w   = (const float*)d_in[13];
    const float* fc1b   = (const float*)d_in[14];
    const float* fc2w   = (const float*)d_in[15];
    const float* fc2b   = (const float*)d_in[16];
    float* out = (float*)d_out;

    float* zbuf    = (float*)d_ws;                       // 4M floats; reused as head partials (512*8192)
    float* ybuf    = zbuf + (size_t)MM * 512;            // 4M floats
    int*   row_cnt = (int*)(ybuf + (size_t)MM * 512);    // 8192
    float* stats   = (float*)(row_cnt + 8192);           // 128: [sum1|sq1|sum2|sq2]
    int*   row_ptr = (int*)(stats + 128);                // 8193
    int*   cursor  = row_ptr + 8193;                     // 8192
    int*   csr_col = cursor + 8192;                      // 131072
    float* csr_val = (float*)(csr_col + NNZ);            // 131072
    float* red     = csr_val + NNZ;                      // 65536

    // zero row_cnt + stats (contiguous 8320 words)
    k_zero<<<(8320 + 255) / 256, 256, 0, stream>>>((float*)row_cnt, 8320);
    // CSR build
    k_hist<<<NNZ / 256, 256, 0, stream>>>(erow, row_cnt);
    k_scan<<<1, 1024, 0, stream>>>(row_cnt, row_ptr, cursor);
    k_scatter<<<NNZ / 256, 256, 0, stream>>>(erow, ecol, evalp, cursor, csr_col, csr_val);
    // layer 1 (linear first — exact by linearity of segment_sum)
    k_lin1<<<4096, 256, 0, stream>>>(inputs, W1, zbuf);
    k_spmm<<<2048, 256, 0, stream>>>(zbuf, row_ptr, csr_col, csr_val, ybuf);
    k_stats<<<512, 256, 0, stream>>>(ybuf, stats);
    // layer 2
    k_lin2<<<2048, 256, 0, stream>>>(ybuf, stats, g1, be1, W2, zbuf);
    k_spmm<<<2048, 256, 0, stream>>>(zbuf, row_ptr, csr_col, csr_val, ybuf);
    k_stats<<<512, 256, 0, stream>>>(ybuf, stats + 64);
    // head: zbuf is dead now — reuse for partials
    k_head<<<512, 256, 0, stream>>>(ybuf, stats + 64, g2, be2, fc1w, zbuf);
    k_red<<<256, 256, 0, stream>>>(zbuf, red);
    k_final<<<16, 512, 0, stream>>>(red, ex, fc1w, fc1b, fc2w, fc2b, out);
}

// Round 3
// 878.608 us; speedup vs baseline: 1.0338x; 1.0338x over previous
//
#include <hip/hip_runtime.h>

#define MM 8192
#define BATCH 16
#define HIDN 32
#define WIN 64
#define NNZ 131072
#define EXTRA 32
#define EPS 1e-5f
#define NSTAT 131072.0f   // BATCH*MM

// ---------- utility ----------
__global__ void k_zero(float* p, int n) {
    int i = blockIdx.x * 256 + threadIdx.x;
    if (i < n) p[i] = 0.f;
}

// ---------- CSR build ----------
__global__ void k_hist(const int* __restrict__ row, int* cnt) {
    int e = blockIdx.x * 256 + threadIdx.x;
    atomicAdd(&cnt[row[e]], 1);
}

__global__ void k_scan(const int* __restrict__ cnt, int* __restrict__ ptr, int* __restrict__ cursor) {
    __shared__ int part[1024];
    int t = threadIdx.x;
    int base = t * 8;
    int pre[8];
    int s = 0;
#pragma unroll
    for (int i = 0; i < 8; i++) { pre[i] = s; s += cnt[base + i]; }
    part[t] = s;
    __syncthreads();
    for (int off = 1; off < 1024; off <<= 1) {
        int v = (t >= off) ? part[t - off] : 0;
        __syncthreads();
        part[t] += v;
        __syncthreads();
    }
    int offs = (t == 0) ? 0 : part[t - 1];
#pragma unroll
    for (int i = 0; i < 8; i++) {
        ptr[base + i] = offs + pre[i];
        cursor[base + i] = offs + pre[i];
    }
    if (t == 1023) ptr[8192] = part[1023];
}

__global__ void k_scatter(const int* __restrict__ row, const int* __restrict__ col,
                          const float* __restrict__ val, int* cursor,
                          int* __restrict__ csr_col, float* __restrict__ csr_val) {
    int e = blockIdx.x * 256 + threadIdx.x;
    int r = row[e];
    int p = atomicAdd(&cursor[r], 1);
    csr_col[p] = col[e];
    csr_val[p] = val[e];
}

// ---------- layer 1 linear: z[m*512 + b*32 + h] = sum_f x[b,m,f] * W1[f,h] ----------
__global__ __launch_bounds__(256) void k_lin1(const float* __restrict__ x,
                                              const float* __restrict__ W1,
                                              float* __restrict__ z) {
    __shared__ float xs[32 * 64];
    int t = threadIdx.x;
    int p0 = blockIdx.x * 32;                 // pair index p = b*M + m
    const float4* x4 = (const float4*)(x + (size_t)p0 * 64);
    float4* xs4 = (float4*)xs;
    xs4[t] = x4[t];
    xs4[t + 256] = x4[t + 256];
    int lane = t & 63;
    int h = lane & 31;
    int sub = lane >> 5;
    int wv = t >> 6;
    float wcol[64];
#pragma unroll
    for (int f = 0; f < 64; f++) wcol[f] = W1[f * 32 + h];
    __syncthreads();
    int b = p0 >> 13;
    int m0 = p0 & 8191;
#pragma unroll
    for (int it = 0; it < 4; it++) {
        int pl = wv * 8 + it * 2 + sub;       // local pair 0..31
        const float4* xr = (const float4*)(xs + pl * 64);
        float acc = 0.f;
#pragma unroll
        for (int i = 0; i < 16; i++) {
            float4 v = xr[i];
            acc += v.x * wcol[4*i] + v.y * wcol[4*i+1] + v.z * wcol[4*i+2] + v.w * wcol[4*i+3];
        }
        z[(size_t)(m0 + pl) * 512 + b * 32 + h] = acc;
    }
}

// ---------- SpMM + fused channel stats ----------
// y[r,:] = sum_{e in row r} val_e * z[col_e,:]  (width 512)
// st: 8 copies x [32 sum | 32 sumsq], copy = blockIdx & 7
__global__ __launch_bounds__(256) void k_spmm(const float* __restrict__ z,
                                              const int* __restrict__ ptr,
                                              const int* __restrict__ cols,
                                              const float* __restrict__ vals,
                                              float* __restrict__ y,
                                              float* __restrict__ st) {
    __shared__ float ls[64];
    int t = threadIdx.x;
    if (t < 64) ls[t] = 0.f;
    int lane = t & 63;
    int r = blockIdx.x * 4 + (t >> 6);
    int e0 = ptr[r], e1 = ptr[r + 1];
    float4 a0 = {0.f, 0.f, 0.f, 0.f};
    float4 a1 = {0.f, 0.f, 0.f, 0.f};
    const float4* z4 = (const float4*)z;
    for (int base = e0; base < e1; base += 64) {
        int n = e1 - base; if (n > 64) n = 64;
        int myc = 0; float myv = 0.f;
        if (lane < n) { myc = cols[base + lane]; myv = vals[base + lane]; }
        for (int j = 0; j < n; j++) {
            int c = __shfl(myc, j, 64);
            float v = __shfl(myv, j, 64);
            float4 b0 = z4[(size_t)c * 128 + lane];
            float4 b1 = z4[(size_t)c * 128 + 64 + lane];
            a0.x += v * b0.x; a0.y += v * b0.y; a0.z += v * b0.z; a0.w += v * b0.w;
            a1.x += v * b1.x; a1.y += v * b1.y; a1.z += v * b1.z; a1.w += v * b1.w;
        }
    }
    float4* y4 = (float4*)y;
    y4[(size_t)r * 128 + lane] = a0;
    y4[(size_t)r * 128 + 64 + lane] = a1;
    // fused channel stats: a0 covers cols 4*lane..+3, a1 covers 256+4*lane..+3;
    // channel = col & 31 = 4*(lane&7)+i for component i -> same for a0/a1.
    float4 s = {a0.x + a1.x, a0.y + a1.y, a0.z + a1.z, a0.w + a1.w};
    float4 q = {a0.x*a0.x + a1.x*a1.x, a0.y*a0.y + a1.y*a1.y,
                a0.z*a0.z + a1.z*a1.z, a0.w*a0.w + a1.w*a1.w};
#pragma unroll
    for (int off = 8; off <= 32; off <<= 1) {
        s.x += __shfl_xor(s.x, off, 64); s.y += __shfl_xor(s.y, off, 64);
        s.z += __shfl_xor(s.z, off, 64); s.w += __shfl_xor(s.w, off, 64);
        q.x += __shfl_xor(q.x, off, 64); q.y += __shfl_xor(q.y, off, 64);
        q.z += __shfl_xor(q.z, off, 64); q.w += __shfl_xor(q.w, off, 64);
    }
    __syncthreads();                          // ls init visible
    if (lane < 8) {
        int ch = lane * 4;
        atomicAdd(&ls[ch + 0], s.x); atomicAdd(&ls[ch + 1], s.y);
        atomicAdd(&ls[ch + 2], s.z); atomicAdd(&ls[ch + 3], s.w);
        atomicAdd(&ls[32 + ch + 0], q.x); atomicAdd(&ls[32 + ch + 1], q.y);
        atomicAdd(&ls[32 + ch + 2], q.z); atomicAdd(&ls[32 + ch + 3], q.w);
    }
    __syncthreads();
    if (t < 64) atomicAdd(&st[(blockIdx.x & 7) * 64 + t], ls[t]);
}

__device__ inline void bn_coef(const float* st, const float* g, const float* be,
                               int ch, float& a, float& c) {
    float s1 = 0.f, s2 = 0.f;
#pragma unroll
    for (int cp = 0; cp < 8; cp++) { s1 += st[cp * 64 + ch]; s2 += st[cp * 64 + 32 + ch]; }
    float mean = s1 * (1.f / NSTAT);
    float var = s2 * (1.f / NSTAT) - mean * mean;
    a = g[ch] * rsqrtf(var + EPS);
    c = be[ch] - mean * a;
}

// ---------- BN1+ReLU fused with layer-2 linear ----------
__global__ __launch_bounds__(256) void k_lin2(const float* __restrict__ y,
                                              const float* __restrict__ st,
                                              const float* __restrict__ g,
                                              const float* __restrict__ be,
                                              const float* __restrict__ W2,
                                              float* __restrict__ z) {
    __shared__ float xs[64 * 32];
    int t = threadIdx.x;
    int ch = t & 31;
    float a, c;
    bn_coef(st, g, be, ch, a, c);
    int q0 = blockIdx.x * 64;                 // q = m*16 + b
    const float* src = y + (size_t)q0 * 32;
#pragma unroll
    for (int i = 0; i < 8; i++) {
        float v = src[t + i * 256];
        xs[t + i * 256] = fmaxf(a * v + c, 0.f);
    }
    int lane = t & 63;
    int h2 = lane & 31;
    int sub = lane >> 5;
    int wv = t >> 6;
    float wcol[32];
#pragma unroll
    for (int h = 0; h < 32; h++) wcol[h] = W2[h * 32 + h2];
    __syncthreads();
    float* zo = z + (size_t)q0 * 32;
#pragma unroll
    for (int it = 0; it < 8; it++) {
        int ql = wv * 16 + it * 2 + sub;
        const float4* xr = (const float4*)(xs + ql * 32);
        float acc = 0.f;
#pragma unroll
        for (int i = 0; i < 8; i++) {
            float4 v = xr[i];
            acc += v.x * wcol[4*i] + v.y * wcol[4*i+1] + v.z * wcol[4*i+2] + v.w * wcol[4*i+3];
        }
        zo[ql * 32 + h2] = acc;
    }
}

// ---------- head partials ----------
__global__ __launch_bounds__(256) void k_head(const float* __restrict__ y,
                                              const float* __restrict__ st,
                                              const float* __restrict__ g,
                                              const float* __restrict__ be,
                                              const float* __restrict__ fw,
                                              float* __restrict__ partial) {
    __shared__ float xsh[16 * 512];           // stage: xsh[mi*512 + h*16 + b]; reused as merge buf
    int t = threadIdx.x;
    int ch = t & 31;
    float a, c;
    bn_coef(st, g, be, ch, a, c);
    int m0 = blockIdx.x * 16;
#pragma unroll
    for (int mi = 0; mi < 16; mi++) {
        int m = m0 + mi;
        float v0 = y[(size_t)m * 512 + t];
        float v1 = y[(size_t)m * 512 + t + 256];
        xsh[mi * 512 + ch * 16 + (t >> 5)]     = fmaxf(a * v0 + c, 0.f);
        xsh[mi * 512 + ch * 16 + (t >> 5) + 8] = fmaxf(a * v1 + c, 0.f);
    }
    __syncthreads();
    int tcol = t & 127;                       // float4 column 0..127
    int half = t >> 7;                        // 0 or 1
    float4 acc[16];
#pragma unroll
    for (int b = 0; b < 16; b++) acc[b] = make_float4(0.f, 0.f, 0.f, 0.f);
    const float4* fw4 = (const float4*)fw;
    for (int mi = half * 8; mi < half * 8 + 8; mi++) {
        int m = m0 + mi;
        const float* xrow = xsh + mi * 512;
#pragma unroll 4
        for (int h = 0; h < 32; h++) {
            float4 w = fw4[(size_t)(m * 32 + h) * 128 + tcol];
            const float4* lt4 = (const float4*)(xrow + h * 16);
#pragma unroll
            for (int i = 0; i < 4; i++) {
                float4 Xi = lt4[i];
                acc[4*i+0].x += Xi.x * w.x; acc[4*i+0].y += Xi.x * w.y; acc[4*i+0].z += Xi.x * w.z; acc[4*i+0].w += Xi.x * w.w;
                acc[4*i+1].x += Xi.y * w.x; acc[4*i+1].y += Xi.y * w.y; acc[4*i+1].z += Xi.y * w.z; acc[4*i+1].w += Xi.y * w.w;
                acc[4*i+2].x += Xi.z * w.x; acc[4*i+2].y += Xi.z * w.y; acc[4*i+2].z += Xi.z * w.z; acc[4*i+2].w += Xi.z * w.w;
                acc[4*i+3].x += Xi.w * w.x; acc[4*i+3].y += Xi.w * w.y; acc[4*i+3].z += Xi.w * w.z; acc[4*i+3].w += Xi.w * w.w;
            }
        }
    }
    __syncthreads();                          // xsh reads done; reuse as merge buffer
    float4* mrg = (float4*)xsh;               // mrg[b*128 + tcol], 16*128 float4 = 32 KB
    if (half == 1) {
#pragma unroll
        for (int b = 0; b < 16; b++) mrg[b * 128 + tcol] = acc[b];
    }
    __syncthreads();
    if (half == 0) {
        float4* po = (float4*)(partial + (size_t)blockIdx.x * 8192);
#pragma unroll
        for (int b = 0; b < 16; b++) {
            float4 o = mrg[b * 128 + tcol];
            acc[b].x += o.x; acc[b].y += o.y; acc[b].z += o.z; acc[b].w += o.w;
            po[b * 128 + tcol] = acc[b];
        }
    }
}

// ---------- fold 512 partials -> 8 ----------
__global__ __launch_bounds__(256) void k_red(const float* __restrict__ partial, float* __restrict__ red) {
    int tid = blockIdx.x * 256 + threadIdx.x;   // 0..65535
    int elem = tid & 8191;
    int p8 = tid >> 13;                         // 0..7
    const float* pp = partial + (size_t)p8 * 64 * 8192 + elem;
    float s0 = 0.f, s1 = 0.f, s2 = 0.f, s3 = 0.f;
    for (int k = 0; k < 64; k += 4) {
        s0 += pp[(size_t)(k + 0) * 8192];
        s1 += pp[(size_t)(k + 1) * 8192];
        s2 += pp[(size_t)(k + 2) * 8192];
        s3 += pp[(size_t)(k + 3) * 8192];
    }
    red[p8 * 8192 + elem] = (s0 + s1) + (s2 + s3);
}

// ---------- finish: sum 8 partials + extras + fc1_b, relu, fc2 ----------
__global__ __launch_bounds__(512) void k_final(const float* __restrict__ red,
                                               const float* __restrict__ ex,
                                               const float* __restrict__ fw,
                                               const float* __restrict__ fb1,
                                               const float* __restrict__ fw2,
                                               const float* __restrict__ fb2,
                                               float* __restrict__ out) {
    int b = blockIdx.x;
    int n = threadIdx.x;
    float v = fb1[n];
#pragma unroll
    for (int p = 0; p < 8; p++) v += red[p * 8192 + b * 512 + n];
#pragma unroll
    for (int e = 0; e < 32; e++)
        v += ex[b * 32 + e] * fw[(size_t)(262144 + e) * 512 + n];
    float h = fmaxf(v, 0.f);
    float p0 = h * fw2[n * 2];
    float p1 = h * fw2[n * 2 + 1];
#pragma unroll
    for (int off = 32; off > 0; off >>= 1) {
        p0 += __shfl_xor(p0, off, 64);
        p1 += __shfl_xor(p1, off, 64);
    }
    __shared__ float ls[16];
    int wv = n >> 6;
    if ((n & 63) == 0) { ls[wv * 2] = p0; ls[wv * 2 + 1] = p1; }
    __syncthreads();
    if (n == 0) {
        float s0 = 0.f, s1 = 0.f;
        for (int w = 0; w < 8; w++) { s0 += ls[w * 2]; s1 += ls[w * 2 + 1]; }
        out[b * 2 + 0] = s0 + fb2[0];
        out[b * 2 + 1] = s1 + fb2[1];
    }
}

extern "C" void kernel_launch(void* const* d_in, const int* in_sizes, int n_in,
                              void* d_out, int out_size, void* d_ws, size_t ws_size,
                              hipStream_t stream) {
    const float* inputs = (const float*)d_in[0];
    const float* ex     = (const float*)d_in[1];
    const int*   erow   = (const int*)d_in[2];
    const int*   ecol   = (const int*)d_in[3];
    const float* evalp  = (const float*)d_in[4];
    const float* W1     = (const float*)d_in[5];
    // d_in[6] = b1 (cancels exactly in BN)
    const float* g1     = (const float*)d_in[7];
    const float* be1    = (const float*)d_in[8];
    const float* W2     = (const float*)d_in[9];
    // d_in[10] = b2 (cancels exactly in BN)
    const float* g2     = (const float*)d_in[11];
    const float* be2    = (const float*)d_in[12];
    const float* fc1w   = (const float*)d_in[13];
    const float* fc1b   = (const float*)d_in[14];
    const float* fc2w   = (const float*)d_in[15];
    const float* fc2b   = (const float*)d_in[16];
    float* out = (float*)d_out;

    float* zbuf    = (float*)d_ws;                       // 4M floats; reused as head partials (512*8192)
    float* ybuf    = zbuf + (size_t)MM * 512;            // 4M floats
    int*   row_cnt = (int*)(ybuf + (size_t)MM * 512);    // 8192
    float* stats   = (float*)(row_cnt + 8192);           // 1024: 8 copies x [64] for L1, then 8x[64] for L2
    int*   row_ptr = (int*)(stats + 1024);               // 8193
    int*   cursor  = row_ptr + 8193;                     // 8192
    int*   csr_col = cursor + 8192;                      // 131072
    float* csr_val = (float*)(csr_col + NNZ);            // 131072
    float* red     = csr_val + NNZ;                      // 65536

    // zero row_cnt + stats (contiguous 9216 words)
    k_zero<<<(9216 + 255) / 256, 256, 0, stream>>>((float*)row_cnt, 9216);
    // CSR build
    k_hist<<<NNZ / 256, 256, 0, stream>>>(erow, row_cnt);
    k_scan<<<1, 1024, 0, stream>>>(row_cnt, row_ptr, cursor);
    k_scatter<<<NNZ / 256, 256, 0, stream>>>(erow, ecol, evalp, cursor, csr_col, csr_val);
    // layer 1 (linear first — exact by linearity of segment_sum)
    k_lin1<<<4096, 256, 0, stream>>>(inputs, W1, zbuf);
    k_spmm<<<2048, 256, 0, stream>>>(zbuf, row_ptr, csr_col, csr_val, ybuf, stats);
    // layer 2
    k_lin2<<<2048, 256, 0, stream>>>(ybuf, stats, g1, be1, W2, zbuf);
    k_spmm<<<2048, 256, 0, stream>>>(zbuf, row_ptr, csr_col, csr_val, ybuf, stats + 512);
    // head: zbuf is dead now — reuse for partials
    k_head<<<512, 256, 0, stream>>>(ybuf, stats + 512, g2, be2, fc1w, zbuf);
    k_red<<<256, 256, 0, stream>>>(zbuf, red);
    k_final<<<16, 512, 0, stream>>>(red, ex, fc1w, fc1b, fc2w, fc2b, out);
}

// Round 4
// 863.126 us; speedup vs baseline: 1.0524x; 1.0179x over previous
//
#include <hip/hip_runtime.h>

#define MM 8192
#define BATCH 16
#define HIDN 32
#define WIN 64
#define NNZ 131072
#define EXTRA 32
#define EPS 1e-5f
#define NSTAT 131072.0f   // BATCH*MM

// ---------- bf16 helpers (RNE) ----------
__device__ inline unsigned short f2bf(float f) {
    unsigned u = __float_as_uint(f);
    unsigned r = u + 0x7fffu + ((u >> 16) & 1u);
    return (unsigned short)(r >> 16);
}
__device__ inline float bflo(unsigned u) { return __uint_as_float(u << 16); }
__device__ inline float bfhi(unsigned u) { return __uint_as_float(u & 0xffff0000u); }

// ---------- utility ----------
__global__ void k_zero(float* p, int n) {
    int i = blockIdx.x * 256 + threadIdx.x;
    if (i < n) p[i] = 0.f;
}

// ---------- CSR build ----------
__global__ void k_hist(const int* __restrict__ row, int* cnt) {
    int e = blockIdx.x * 256 + threadIdx.x;
    atomicAdd(&cnt[row[e]], 1);
}

__global__ void k_scan(const int* __restrict__ cnt, int* __restrict__ ptr, int* __restrict__ cursor) {
    __shared__ int part[1024];
    int t = threadIdx.x;
    int base = t * 8;
    int pre[8];
    int s = 0;
#pragma unroll
    for (int i = 0; i < 8; i++) { pre[i] = s; s += cnt[base + i]; }
    part[t] = s;
    __syncthreads();
    for (int off = 1; off < 1024; off <<= 1) {
        int v = (t >= off) ? part[t - off] : 0;
        __syncthreads();
        part[t] += v;
        __syncthreads();
    }
    int offs = (t == 0) ? 0 : part[t - 1];
#pragma unroll
    for (int i = 0; i < 8; i++) {
        ptr[base + i] = offs + pre[i];
        cursor[base + i] = offs + pre[i];
    }
    if (t == 1023) ptr[8192] = part[1023];
}

__global__ void k_scatter(const int* __restrict__ row, const int* __restrict__ col,
                          const float* __restrict__ val, int* cursor,
                          int* __restrict__ csr_col, float* __restrict__ csr_val) {
    int e = blockIdx.x * 256 + threadIdx.x;
    int r = row[e];
    int p = atomicAdd(&cursor[r], 1);
    csr_col[p] = col[e];
    csr_val[p] = val[e];
}

// ---------- layer 1 linear: z[m*512 + b*32 + h] = bf16( sum_f x[b,m,f] * W1[f,h] ) ----------
__global__ __launch_bounds__(256) void k_lin1(const float* __restrict__ x,
                                              const float* __restrict__ W1,
                                              unsigned short* __restrict__ z) {
    __shared__ float xs[32 * 64];
    int t = threadIdx.x;
    int p0 = blockIdx.x * 32;                 // pair index p = b*M + m
    const float4* x4 = (const float4*)(x + (size_t)p0 * 64);
    float4* xs4 = (float4*)xs;
    xs4[t] = x4[t];
    xs4[t + 256] = x4[t + 256];
    int lane = t & 63;
    int h = lane & 31;
    int sub = lane >> 5;
    int wv = t >> 6;
    float wcol[64];
#pragma unroll
    for (int f = 0; f < 64; f++) wcol[f] = W1[f * 32 + h];
    __syncthreads();
    int b = p0 >> 13;
    int m0 = p0 & 8191;
#pragma unroll
    for (int it = 0; it < 4; it++) {
        int pl = wv * 8 + it * 2 + sub;       // local pair 0..31
        const float4* xr = (const float4*)(xs + pl * 64);
        float acc = 0.f;
#pragma unroll
        for (int i = 0; i < 16; i++) {
            float4 v = xr[i];
            acc += v.x * wcol[4*i] + v.y * wcol[4*i+1] + v.z * wcol[4*i+2] + v.w * wcol[4*i+3];
        }
        z[(size_t)(m0 + pl) * 512 + b * 32 + h] = f2bf(acc);
    }
}

// ---------- SpMM (bf16 in/out, fp32 accum) + fused channel stats ----------
// y[r,:] = sum_{e in row r} val_e * z[col_e,:]  (width 512 bf16; one wave per row, 8 cols/lane)
// st: 8 copies x [32 sum | 32 sumsq], copy = blockIdx & 7
__global__ __launch_bounds__(256) void k_spmm(const unsigned short* __restrict__ z,
                                              const int* __restrict__ ptr,
                                              const int* __restrict__ cols,
                                              const float* __restrict__ vals,
                                              unsigned short* __restrict__ y,
                                              float* __restrict__ st) {
    __shared__ float ls[64];
    int t = threadIdx.x;
    if (t < 64) ls[t] = 0.f;
    int lane = t & 63;
    int r = blockIdx.x * 4 + (t >> 6);
    int e0 = ptr[r], e1 = ptr[r + 1];
    float a[8];
#pragma unroll
    for (int i = 0; i < 8; i++) a[i] = 0.f;
    const uint4* z4 = (const uint4*)z;        // 64 uint4 per row
    for (int base = e0; base < e1; base += 64) {
        int n = e1 - base; if (n > 64) n = 64;
        int myc = 0; float myv = 0.f;
        if (lane < n) { myc = cols[base + lane]; myv = vals[base + lane]; }
        for (int j = 0; j < n; j++) {
            int c = __shfl(myc, j, 64);
            float v = __shfl(myv, j, 64);
            uint4 B = z4[(size_t)c * 64 + lane];
            a[0] += v * bflo(B.x); a[1] += v * bfhi(B.x);
            a[2] += v * bflo(B.y); a[3] += v * bfhi(B.y);
            a[4] += v * bflo(B.z); a[5] += v * bfhi(B.z);
            a[6] += v * bflo(B.w); a[7] += v * bfhi(B.w);
        }
    }
    uint4 o;
    o.x = ((unsigned)f2bf(a[1]) << 16) | f2bf(a[0]);
    o.y = ((unsigned)f2bf(a[3]) << 16) | f2bf(a[2]);
    o.z = ((unsigned)f2bf(a[5]) << 16) | f2bf(a[4]);
    o.w = ((unsigned)f2bf(a[7]) << 16) | f2bf(a[6]);
    ((uint4*)y)[(size_t)r * 64 + lane] = o;
    // stats: col = 8*lane + i -> ch = 8*(lane&3) + i
    float q[8];
#pragma unroll
    for (int i = 0; i < 8; i++) q[i] = a[i] * a[i];
#pragma unroll
    for (int off = 4; off <= 32; off <<= 1) {
#pragma unroll
        for (int i = 0; i < 8; i++) {
            a[i] += __shfl_xor(a[i], off, 64);
            q[i] += __shfl_xor(q[i], off, 64);
        }
    }
    __syncthreads();                          // ls init visible
    if (lane < 4) {
        int cb = lane * 8;
#pragma unroll
        for (int i = 0; i < 8; i++) {
            atomicAdd(&ls[cb + i], a[i]);
            atomicAdd(&ls[32 + cb + i], q[i]);
        }
    }
    __syncthreads();
    if (t < 64) atomicAdd(&st[(blockIdx.x & 7) * 64 + t], ls[t]);
}

__device__ inline void bn_coef(const float* st, const float* g, const float* be,
                               int ch, float& a, float& c) {
    float s1 = 0.f, s2 = 0.f;
#pragma unroll
    for (int cp = 0; cp < 8; cp++) { s1 += st[cp * 64 + ch]; s2 += st[cp * 64 + 32 + ch]; }
    float mean = s1 * (1.f / NSTAT);
    float var = s2 * (1.f / NSTAT) - mean * mean;
    a = g[ch] * rsqrtf(var + EPS);
    c = be[ch] - mean * a;
}

// ---------- BN1+ReLU fused with layer-2 linear (bf16 y in, bf16 z out) ----------
__global__ __launch_bounds__(256) void k_lin2(const unsigned short* __restrict__ y,
                                              const float* __restrict__ st,
                                              const float* __restrict__ g,
                                              const float* __restrict__ be,
                                              const float* __restrict__ W2,
                                              unsigned short* __restrict__ z) {
    __shared__ float xs[64 * 32];
    int t = threadIdx.x;
    int q0 = blockIdx.x * 64;                 // q = m*16 + b
    // load 8 bf16 per thread: elements q0*32 + t*8 .. +7; ch = 8*(t&3)+i
    uint4 B = ((const uint4*)(y + (size_t)q0 * 32))[t];
    float vv[8];
    vv[0] = bflo(B.x); vv[1] = bfhi(B.x); vv[2] = bflo(B.y); vv[3] = bfhi(B.y);
    vv[4] = bflo(B.z); vv[5] = bfhi(B.z); vv[6] = bflo(B.w); vv[7] = bfhi(B.w);
    int cb = 8 * (t & 3);
#pragma unroll
    for (int i = 0; i < 8; i++) {
        float a, c;
        bn_coef(st, g, be, cb + i, a, c);
        xs[t * 8 + i] = fmaxf(a * vv[i] + c, 0.f);
    }
    int lane = t & 63;
    int h2 = lane & 31;
    int sub = lane >> 5;
    int wv = t >> 6;
    float wcol[32];
#pragma unroll
    for (int h = 0; h < 32; h++) wcol[h] = W2[h * 32 + h2];
    __syncthreads();
    unsigned short* zo = z + (size_t)q0 * 32;
#pragma unroll
    for (int it = 0; it < 8; it++) {
        int ql = wv * 16 + it * 2 + sub;
        const float4* xr = (const float4*)(xs + ql * 32);
        float acc = 0.f;
#pragma unroll
        for (int i = 0; i < 8; i++) {
            float4 v = xr[i];
            acc += v.x * wcol[4*i] + v.y * wcol[4*i+1] + v.z * wcol[4*i+2] + v.w * wcol[4*i+3];
        }
        zo[ql * 32 + h2] = f2bf(acc);
    }
}

// ---------- head partials (bf16 y in) ----------
__global__ __launch_bounds__(256) void k_head(const unsigned short* __restrict__ y,
                                              const float* __restrict__ st,
                                              const float* __restrict__ g,
                                              const float* __restrict__ be,
                                              const float* __restrict__ fw,
                                              float* __restrict__ partial) {
    __shared__ float xsh[16 * 512];           // stage: xsh[mi*512 + h*16 + b]; reused as merge buf
    int t = threadIdx.x;
    int ch0 = (2 * t) & 31;                   // even; cols 2t, 2t+1 -> ch0, ch0+1
    float a0c, c0c, a1c, c1c;
    bn_coef(st, g, be, ch0, a0c, c0c);
    bn_coef(st, g, be, ch0 + 1, a1c, c1c);
    int bidx = (2 * t) >> 5;                  // same for col 2t+1
    int m0 = blockIdx.x * 16;
#pragma unroll
    for (int mi = 0; mi < 16; mi++) {
        int m = m0 + mi;
        unsigned B = ((const unsigned*)(y + (size_t)m * 512))[t];
        xsh[mi * 512 + ch0 * 16 + bidx]       = fmaxf(a0c * bflo(B) + c0c, 0.f);
        xsh[mi * 512 + (ch0 + 1) * 16 + bidx] = fmaxf(a1c * bfhi(B) + c1c, 0.f);
    }
    __syncthreads();
    int tcol = t & 127;                       // float4 column 0..127
    int half = t >> 7;                        // 0 or 1
    float4 acc[16];
#pragma unroll
    for (int b = 0; b < 16; b++) acc[b] = make_float4(0.f, 0.f, 0.f, 0.f);
    const float4* fw4 = (const float4*)fw;
    for (int mi = half * 8; mi < half * 8 + 8; mi++) {
        int m = m0 + mi;
        const float* xrow = xsh + mi * 512;
#pragma unroll 4
        for (int h = 0; h < 32; h++) {
            float4 w = fw4[(size_t)(m * 32 + h) * 128 + tcol];
            const float4* lt4 = (const float4*)(xrow + h * 16);
#pragma unroll
            for (int i = 0; i < 4; i++) {
                float4 Xi = lt4[i];
                acc[4*i+0].x += Xi.x * w.x; acc[4*i+0].y += Xi.x * w.y; acc[4*i+0].z += Xi.x * w.z; acc[4*i+0].w += Xi.x * w.w;
                acc[4*i+1].x += Xi.y * w.x; acc[4*i+1].y += Xi.y * w.y; acc[4*i+1].z += Xi.y * w.z; acc[4*i+1].w += Xi.y * w.w;
                acc[4*i+2].x += Xi.z * w.x; acc[4*i+2].y += Xi.z * w.y; acc[4*i+2].z += Xi.z * w.z; acc[4*i+2].w += Xi.z * w.w;
                acc[4*i+3].x += Xi.w * w.x; acc[4*i+3].y += Xi.w * w.y; acc[4*i+3].z += Xi.w * w.z; acc[4*i+3].w += Xi.w * w.w;
            }
        }
    }
    __syncthreads();                          // xsh reads done; reuse as merge buffer
    float4* mrg = (float4*)xsh;               // mrg[b*128 + tcol], 16*128 float4 = 32 KB
    if (half == 1) {
#pragma unroll
        for (int b = 0; b < 16; b++) mrg[b * 128 + tcol] = acc[b];
    }
    __syncthreads();
    if (half == 0) {
        float4* po = (float4*)(partial + (size_t)blockIdx.x * 8192);
#pragma unroll
        for (int b = 0; b < 16; b++) {
            float4 o = mrg[b * 128 + tcol];
            acc[b].x += o.x; acc[b].y += o.y; acc[b].z += o.z; acc[b].w += o.w;
            po[b * 128 + tcol] = acc[b];
        }
    }
}

// ---------- fold 512 partials -> 8 ----------
__global__ __launch_bounds__(256) void k_red(const float* __restrict__ partial, float* __restrict__ red) {
    int tid = blockIdx.x * 256 + threadIdx.x;   // 0..65535
    int elem = tid & 8191;
    int p8 = tid >> 13;                         // 0..7
    const float* pp = partial + (size_t)p8 * 64 * 8192 + elem;
    float s0 = 0.f, s1 = 0.f, s2 = 0.f, s3 = 0.f;
    for (int k = 0; k < 64; k += 4) {
        s0 += pp[(size_t)(k + 0) * 8192];
        s1 += pp[(size_t)(k + 1) * 8192];
        s2 += pp[(size_t)(k + 2) * 8192];
        s3 += pp[(size_t)(k + 3) * 8192];
    }
    red[p8 * 8192 + elem] = (s0 + s1) + (s2 + s3);
}

// ---------- finish: sum 8 partials + extras + fc1_b, relu, fc2 ----------
__global__ __launch_bounds__(512) void k_final(const float* __restrict__ red,
                                               const float* __restrict__ ex,
                                               const float* __restrict__ fw,
                                               const float* __restrict__ fb1,
                                               const float* __restrict__ fw2,
                                               const float* __restrict__ fb2,
                                               float* __restrict__ out) {
    int b = blockIdx.x;
    int n = threadIdx.x;
    float v = fb1[n];
#pragma unroll
    for (int p = 0; p < 8; p++) v += red[p * 8192 + b * 512 + n];
#pragma unroll
    for (int e = 0; e < 32; e++)
        v += ex[b * 32 + e] * fw[(size_t)(262144 + e) * 512 + n];
    float h = fmaxf(v, 0.f);
    float p0 = h * fw2[n * 2];
    float p1 = h * fw2[n * 2 + 1];
#pragma unroll
    for (int off = 32; off > 0; off >>= 1) {
        p0 += __shfl_xor(p0, off, 64);
        p1 += __shfl_xor(p1, off, 64);
    }
    __shared__ float ls[16];
    int wv = n >> 6;
    if ((n & 63) == 0) { ls[wv * 2] = p0; ls[wv * 2 + 1] = p1; }
    __syncthreads();
    if (n == 0) {
        float s0 = 0.f, s1 = 0.f;
        for (int w = 0; w < 8; w++) { s0 += ls[w * 2]; s1 += ls[w * 2 + 1]; }
        out[b * 2 + 0] = s0 + fb2[0];
        out[b * 2 + 1] = s1 + fb2[1];
    }
}

extern "C" void kernel_launch(void* const* d_in, const int* in_sizes, int n_in,
                              void* d_out, int out_size, void* d_ws, size_t ws_size,
                              hipStream_t stream) {
    const float* inputs = (const float*)d_in[0];
    const float* ex     = (const float*)d_in[1];
    const int*   erow   = (const int*)d_in[2];
    const int*   ecol   = (const int*)d_in[3];
    const float* evalp  = (const float*)d_in[4];
    const float* W1     = (const float*)d_in[5];
    // d_in[6] = b1 (cancels exactly in BN)
    const float* g1     = (const float*)d_in[7];
    const float* be1    = (const float*)d_in[8];
    const float* W2     = (const float*)d_in[9];
    // d_in[10] = b2 (cancels exactly in BN)
    const float* g2     = (const float*)d_in[11];
    const float* be2    = (const float*)d_in[12];
    const float* fc1w   = (const float*)d_in[13];
    const float* fc1b   = (const float*)d_in[14];
    const float* fc2w   = (const float*)d_in[15];
    const float* fc2b   = (const float*)d_in[16];
    float* out = (float*)d_out;

    float* zbuf    = (float*)d_ws;                       // 4M-float region; bf16 z + reused as head partials
    float* ybuf    = zbuf + (size_t)MM * 512;            // 4M-float region; bf16 y
    int*   row_cnt = (int*)(ybuf + (size_t)MM * 512);    // 8192
    float* stats   = (float*)(row_cnt + 8192);           // 1024: 8 copies x [64] for L1, then 8x[64] for L2
    int*   row_ptr = (int*)(stats + 1024);               // 8193
    int*   cursor  = row_ptr + 8193;                     // 8192
    int*   csr_col = cursor + 8192;                      // 131072
    float* csr_val = (float*)(csr_col + NNZ);            // 131072
    float* red     = csr_val + NNZ;                      // 65536

    unsigned short* zb16 = (unsigned short*)zbuf;
    unsigned short* yb16 = (unsigned short*)ybuf;

    // zero row_cnt + stats (contiguous 9216 words)
    k_zero<<<(9216 + 255) / 256, 256, 0, stream>>>((float*)row_cnt, 9216);
    // CSR build
    k_hist<<<NNZ / 256, 256, 0, stream>>>(erow, row_cnt);
    k_scan<<<1, 1024, 0, stream>>>(row_cnt, row_ptr, cursor);
    k_scatter<<<NNZ / 256, 256, 0, stream>>>(erow, ecol, evalp, cursor, csr_col, csr_val);
    // layer 1 (linear first — exact by linearity of segment_sum)
    k_lin1<<<4096, 256, 0, stream>>>(inputs, W1, zb16);
    k_spmm<<<2048, 256, 0, stream>>>(zb16, row_ptr, csr_col, csr_val, yb16, stats);
    // layer 2
    k_lin2<<<2048, 256, 0, stream>>>(yb16, stats, g1, be1, W2, zb16);
    k_spmm<<<2048, 256, 0, stream>>>(zb16, row_ptr, csr_col, csr_val, yb16, stats + 512);
    // head: zbuf region is dead now — reuse for fp32 partials
    k_head<<<512, 256, 0, stream>>>(yb16, stats + 512, g2, be2, fc1w, zbuf);
    k_red<<<256, 256, 0, stream>>>(zbuf, red);
    k_final<<<16, 512, 0, stream>>>(red, ex, fc1w, fc1b, fc2w, fc2b, out);
}